// Round 1
// baseline (191.496 us; speedup 1.0000x reference)
//
#include <hip/hip_runtime.h>
#include <math.h>

#define BATCH 16384
#define NW 10
#define NENC 4
#define DEPTH 2

// One wave (64 lanes) per batch element. State amplitude index:
//   idx (10 bits) = (r << 6) | lane,  r in [0,16) held as re[r], im[r] per lane.
// Wire w lives at bit position (9-w):
//   w=0..3  -> r bits 3..0  (masks 8,4,2,1)   [register wires]
//   w=4..9  -> lane bits 5..0 (masks 32..1)   [lane wires, shfl_xor]

__global__ __launch_bounds__(256) void qsim_kernel(
    const float* __restrict__ x, const float* __restrict__ theta,
    float* __restrict__ out)
{
    const int lane = threadIdx.x & 63;
    const int b = (blockIdx.x * blockDim.x + threadIdx.x) >> 6;  // wave id = batch idx

    float re[16], im[16];
#pragma unroll
    for (int r = 0; r < 16; ++r) { re[r] = 0.0f; im[r] = 0.0f; }
    if (lane == 0) re[0] = 1.0f;   // |0...0>

    // ---- encoding: RX(x[b][i]) on wires 0..3 (register wires) ----
#pragma unroll
    for (int i = 0; i < NENC; ++i) {
        const float h = 0.5f * x[b * NENC + i];
        const float c = __cosf(h), s = __sinf(h);
        const int m = 8 >> i;
#pragma unroll
        for (int r = 0; r < 16; ++r) {
            if (!(r & m)) {
                const int r1 = r | m;
                const float a0r = re[r],  a0i = im[r];
                const float a1r = re[r1], a1i = im[r1];
                re[r]  = c * a0r + s * a1i;
                im[r]  = c * a0i - s * a1r;
                re[r1] = c * a1r + s * a0i;
                im[r1] = c * a1i - s * a0r;
            }
        }
    }

    // ---- shared rotation angles ----
    float ct[NW], st_[NW];
#pragma unroll
    for (int w = 0; w < NW; ++w) {
        const float h = 0.5f * theta[w];
        ct[w] = __cosf(h); st_[w] = __sinf(h);
    }

    // ---- depth layers ----
#pragma unroll 1
    for (int d = 0; d < DEPTH; ++d) {
        // RX on register wires 0..3
#pragma unroll
        for (int w = 0; w < 4; ++w) {
            const float c = ct[w], s = st_[w];
            const int m = 8 >> w;
#pragma unroll
            for (int r = 0; r < 16; ++r) {
                if (!(r & m)) {
                    const int r1 = r | m;
                    const float a0r = re[r],  a0i = im[r];
                    const float a1r = re[r1], a1i = im[r1];
                    re[r]  = c * a0r + s * a1i;
                    im[r]  = c * a0i - s * a1r;
                    re[r1] = c * a1r + s * a0i;
                    im[r1] = c * a1i - s * a0r;
                }
            }
        }
        // RX on lane wires 4..9  (n = c*self + s*i_rot(partner); same both sides)
#pragma unroll
        for (int w = 4; w < 10; ++w) {
            const float c = ct[w], s = st_[w];
            const int lm = 32 >> (w - 4);
#pragma unroll
            for (int r = 0; r < 16; ++r) {
                const float pr = __shfl_xor(re[r], lm, 64);
                const float pi = __shfl_xor(im[r], lm, 64);
                re[r] = c * re[r] + s * pi;
                im[r] = c * im[r] - s * pr;
            }
        }
        // ring CNOTs, in reference order (0,1)(1,2)...(8,9)(9,0)
        // (0,1),(1,2),(2,3): ctrl & tgt in r -> compile-time register swaps
#pragma unroll
        for (int w = 0; w < 3; ++w) {
            const int cm = 8 >> w, tm = 8 >> (w + 1);
#pragma unroll
            for (int r = 0; r < 16; ++r) {
                if ((r & cm) && !(r & tm)) {
                    const int r2 = r | tm;
                    float t;
                    t = re[r]; re[r] = re[r2]; re[r2] = t;
                    t = im[r]; im[r] = im[r2]; im[r2] = t;
                }
            }
        }
        // (3,4): ctrl = r bit0, tgt = lane bit5 -> swap via shuffle on odd regs
#pragma unroll
        for (int r = 0; r < 16; ++r) {
            if (r & 1) {
                re[r] = __shfl_xor(re[r], 32, 64);
                im[r] = __shfl_xor(im[r], 32, 64);
            }
        }
        // (4,5)..(8,9): ctrl & tgt lane bits -> shuffle + per-lane select
#pragma unroll
        for (int w = 4; w < 9; ++w) {
            const int cm = 32 >> (w - 4), tm = 32 >> (w - 3);
            const bool ctl = (lane & cm) != 0;
#pragma unroll
            for (int r = 0; r < 16; ++r) {
                const float pr = __shfl_xor(re[r], tm, 64);
                const float pi = __shfl_xor(im[r], tm, 64);
                re[r] = ctl ? pr : re[r];
                im[r] = ctl ? pi : im[r];
            }
        }
        // (9,0): ctrl = lane bit0, tgt = r bit3 -> lane-predicated reg swap
        {
            const bool ctl = (lane & 1) != 0;
#pragma unroll
            for (int r = 0; r < 8; ++r) {
                const float t0r = re[r], t1r = re[r + 8];
                const float t0i = im[r], t1i = im[r + 8];
                re[r]     = ctl ? t1r : t0r;
                re[r + 8] = ctl ? t0r : t1r;
                im[r]     = ctl ? t1i : t0i;
                im[r + 8] = ctl ? t0i : t1i;
            }
        }
    }

    // ---- probabilities and Z expectations ----
    float p[16];
#pragma unroll
    for (int r = 0; r < 16; ++r) p[r] = re[r] * re[r] + im[r] * im[r];

    float z[NW];
#pragma unroll
    for (int w = 0; w < 4; ++w) {           // sign from register bit
        const int m = 8 >> w;
        float acc = 0.0f;
#pragma unroll
        for (int r = 0; r < 16; ++r) acc += (r & m) ? -p[r] : p[r];
        z[w] = acc;
    }
    float tot = 0.0f;
#pragma unroll
    for (int r = 0; r < 16; ++r) tot += p[r];
#pragma unroll
    for (int w = 4; w < 10; ++w) {          // sign from lane bit only
        const int lm = 32 >> (w - 4);
        z[w] = (lane & lm) ? -tot : tot;
    }

    // wave-wide butterfly reduction of all 10 expectations
#pragma unroll
    for (int w = 0; w < NW; ++w) {
        float v = z[w];
#pragma unroll
        for (int ofs = 32; ofs >= 1; ofs >>= 1)
            v += __shfl_xor(v, ofs, 64);
        z[w] = v;
    }

    if (lane == 0) {
#pragma unroll
        for (int w = 0; w < NW; ++w) out[b * NW + w] = z[w];
    }
}

extern "C" void kernel_launch(void* const* d_in, const int* in_sizes, int n_in,
                              void* d_out, int out_size, void* d_ws, size_t ws_size,
                              hipStream_t stream) {
    const float* x     = (const float*)d_in[0];
    const float* theta = (const float*)d_in[1];
    float* out = (float*)d_out;
    // one wave per batch element; 4 waves (256 threads) per block
    dim3 grid(BATCH / 4), block(256);
    hipLaunchKernelGGL(qsim_kernel, grid, block, 0, stream, x, theta, out);
}

// Round 2
// 79.439 us; speedup vs baseline: 2.4106x; 2.4106x over previous
//
#include <hip/hip_runtime.h>
#include <math.h>

#define BATCH 16384
#define NW 10
#define NENC 4
#define DEPTH 2

// ============================================================================
// Algebraic restructuring:
//   encoded state psi(x) has support on 16 basis states (indices a<<6),
//   psi_a = m_a * (-i)^popc(a), m_a = prod of cos/sin of the 4 encodings.
//   z_w = psi^H (U^H D_w U) psi = sum_{a,b} m_a m_b C_w[a][b],
//   C_w[a][b] = Re( i^(popc(a)-popc(b)) * sum_i sign_w(i) conj(u_a[i]) u_b[i] )
//   (real symmetric).  u_a = U e_{a<<6} is batch-independent.
// k1: 16 waves propagate u_a (verified shuffle simulator, no encoding).
// k2: 256 waves compute C (one wave per (a,b) pair).
// k3: one thread per batch element evaluates the 10 quadratic forms.
// ============================================================================

// ---- kernel 1: basis-column propagation --------------------------------
__global__ __launch_bounds__(256) void k1_basis(const float* __restrict__ theta,
                                                float2* __restrict__ u)
{
    const int lane = threadIdx.x & 63;
    const int a = (blockIdx.x * blockDim.x + threadIdx.x) >> 6;  // 0..15

    float re[16], im[16];
#pragma unroll
    for (int r = 0; r < 16; ++r) { re[r] = 0.0f; im[r] = 0.0f; }
    if (lane == 0) re[a] = 1.0f;     // |a<<6>

    float ct[NW], st_[NW];
#pragma unroll
    for (int w = 0; w < NW; ++w) {
        const float h = 0.5f * theta[w];
        ct[w] = __cosf(h); st_[w] = __sinf(h);
    }

#pragma unroll 1
    for (int d = 0; d < DEPTH; ++d) {
        // RX on register wires 0..3
#pragma unroll
        for (int w = 0; w < 4; ++w) {
            const float c = ct[w], s = st_[w];
            const int m = 8 >> w;
#pragma unroll
            for (int r = 0; r < 16; ++r) {
                if (!(r & m)) {
                    const int r1 = r | m;
                    const float a0r = re[r],  a0i = im[r];
                    const float a1r = re[r1], a1i = im[r1];
                    re[r]  = c * a0r + s * a1i;
                    im[r]  = c * a0i - s * a1r;
                    re[r1] = c * a1r + s * a0i;
                    im[r1] = c * a1i - s * a0r;
                }
            }
        }
        // RX on lane wires 4..9
#pragma unroll
        for (int w = 4; w < 10; ++w) {
            const float c = ct[w], s = st_[w];
            const int lm = 32 >> (w - 4);
#pragma unroll
            for (int r = 0; r < 16; ++r) {
                const float pr = __shfl_xor(re[r], lm, 64);
                const float pi = __shfl_xor(im[r], lm, 64);
                re[r] = c * re[r] + s * pi;
                im[r] = c * im[r] - s * pr;
            }
        }
        // ring CNOTs (0,1)(1,2)(2,3): register swaps
#pragma unroll
        for (int w = 0; w < 3; ++w) {
            const int cm = 8 >> w, tm = 8 >> (w + 1);
#pragma unroll
            for (int r = 0; r < 16; ++r) {
                if ((r & cm) && !(r & tm)) {
                    const int r2 = r | tm;
                    float t;
                    t = re[r]; re[r] = re[r2]; re[r2] = t;
                    t = im[r]; im[r] = im[r2]; im[r2] = t;
                }
            }
        }
        // (3,4): odd registers swap lanes across bit5
#pragma unroll
        for (int r = 0; r < 16; ++r) {
            if (r & 1) {
                re[r] = __shfl_xor(re[r], 32, 64);
                im[r] = __shfl_xor(im[r], 32, 64);
            }
        }
        // (4,5)..(8,9): lane-bit CNOTs
#pragma unroll
        for (int w = 4; w < 9; ++w) {
            const int cm = 32 >> (w - 4), tm = 32 >> (w - 3);
            const bool ctl = (lane & cm) != 0;
#pragma unroll
            for (int r = 0; r < 16; ++r) {
                const float pr = __shfl_xor(re[r], tm, 64);
                const float pi = __shfl_xor(im[r], tm, 64);
                re[r] = ctl ? pr : re[r];
                im[r] = ctl ? pi : im[r];
            }
        }
        // (9,0): lane-bit0 controlled register-bit3 swap
        {
            const bool ctl = (lane & 1) != 0;
#pragma unroll
            for (int r = 0; r < 8; ++r) {
                const float t0r = re[r], t1r = re[r + 8];
                const float t0i = im[r], t1i = im[r + 8];
                re[r]     = ctl ? t1r : t0r;
                re[r + 8] = ctl ? t0r : t1r;
                im[r]     = ctl ? t1i : t0i;
                im[r + 8] = ctl ? t0i : t1i;
            }
        }
    }

#pragma unroll
    for (int r = 0; r < 16; ++r)
        u[a * 1024 + (r << 6) + lane] = make_float2(re[r], im[r]);
}

// ---- kernel 2: Gram matrices with Z signs, phase-folded ----------------
// One wave per (a,b) pair, q = a*16+b.  C layout: [q][12] floats (pad to 48B).
__global__ __launch_bounds__(256) void k2_gram(const float2* __restrict__ u,
                                               float* __restrict__ C)
{
    const int lane = threadIdx.x & 63;
    const int q = (blockIdx.x * blockDim.x + threadIdx.x) >> 6;  // 0..255
    const int a = q >> 4, b = q & 15;

    float Sr[NW], Si[NW];
#pragma unroll
    for (int w = 0; w < NW; ++w) { Sr[w] = 0.0f; Si[w] = 0.0f; }

#pragma unroll
    for (int t = 0; t < 16; ++t) {
        const int i = t * 64 + lane;
        const float2 ua = u[a * 1024 + i];
        const float2 ub = u[b * 1024 + i];
        const float vr = ua.x * ub.x + ua.y * ub.y;   // Re(conj(ua)*ub)
        const float vi = ua.x * ub.y - ua.y * ub.x;   // Im(conj(ua)*ub)
#pragma unroll
        for (int w = 0; w < NW; ++w) {
            const int mask = 1 << (9 - w);
            const float sv = (i & mask) ? -1.0f : 1.0f;
            Sr[w] = fmaf(sv, vr, Sr[w]);
            Si[w] = fmaf(sv, vi, Si[w]);
        }
    }
    // wave butterfly reduction
#pragma unroll
    for (int w = 0; w < NW; ++w) {
        float r = Sr[w], ii = Si[w];
#pragma unroll
        for (int ofs = 32; ofs >= 1; ofs >>= 1) {
            r  += __shfl_xor(r,  ofs, 64);
            ii += __shfl_xor(ii, ofs, 64);
        }
        Sr[w] = r; Si[w] = ii;
    }

    if (lane == 0) {
        const int p = (__popc(a) - __popc(b)) & 3;
#pragma unroll
        for (int w = 0; w < NW; ++w) {
            const float sr = Sr[w], si = Si[w];
            // Re(i^p * (sr + i si))
            const float c = (p == 0) ? sr : (p == 1) ? -si : (p == 2) ? -sr : si;
            C[q * 12 + w] = c;
        }
    }
}

// ---- kernel 3: per-batch quadratic forms -------------------------------
__global__ __launch_bounds__(256) void k3_eval(const float* __restrict__ x,
                                               const float* __restrict__ C,
                                               float* __restrict__ out)
{
    __shared__ float lC[256 * 12];
    for (int i = threadIdx.x; i < 256 * 12; i += 256) lC[i] = C[i];
    __syncthreads();

    const int bidx = blockIdx.x * 256 + threadIdx.x;   // batch element
    const float4 xv = ((const float4*)x)[bidx];

    const float c0 = __cosf(0.5f * xv.x), s0 = __sinf(0.5f * xv.x);
    const float c1 = __cosf(0.5f * xv.y), s1 = __sinf(0.5f * xv.y);
    const float c2 = __cosf(0.5f * xv.z), s2 = __sinf(0.5f * xv.z);
    const float c3 = __cosf(0.5f * xv.w), s3 = __sinf(0.5f * xv.w);

    const float t01[4] = { c0 * c1, c0 * s1, s0 * c1, s0 * s1 };
    const float t23[4] = { c2 * c3, c2 * s3, s2 * c3, s2 * s3 };
    float m[16];
#pragma unroll
    for (int r = 0; r < 16; ++r) m[r] = t01[r >> 2] * t23[r & 3];

    float z[NW];
#pragma unroll
    for (int w = 0; w < NW; ++w) z[w] = 0.0f;

#pragma unroll
    for (int a = 0; a < 16; ++a) {
#pragma unroll
        for (int b = a; b < 16; ++b) {
            const float scale = (a == b) ? 1.0f : 2.0f;   // symmetric fold
            const float p = scale * m[a] * m[b];
            const float* base = &lC[(a * 16 + b) * 12];
            const float4 q0 = *(const float4*)(base + 0);
            const float4 q1 = *(const float4*)(base + 4);
            const float4 q2 = *(const float4*)(base + 8);
            z[0] = fmaf(p, q0.x, z[0]);
            z[1] = fmaf(p, q0.y, z[1]);
            z[2] = fmaf(p, q0.z, z[2]);
            z[3] = fmaf(p, q0.w, z[3]);
            z[4] = fmaf(p, q1.x, z[4]);
            z[5] = fmaf(p, q1.y, z[5]);
            z[6] = fmaf(p, q1.z, z[6]);
            z[7] = fmaf(p, q1.w, z[7]);
            z[8] = fmaf(p, q2.x, z[8]);
            z[9] = fmaf(p, q2.y, z[9]);
        }
    }

#pragma unroll
    for (int w = 0; w < NW; ++w) out[bidx * NW + w] = z[w];
}

extern "C" void kernel_launch(void* const* d_in, const int* in_sizes, int n_in,
                              void* d_out, int out_size, void* d_ws, size_t ws_size,
                              hipStream_t stream) {
    const float* x     = (const float*)d_in[0];
    const float* theta = (const float*)d_in[1];
    float* out = (float*)d_out;

    float2* u = (float2*)d_ws;                                 // 16*1024*8 = 131072 B
    float*  C = (float*)((char*)d_ws + 16 * 1024 * sizeof(float2)); // 256*12*4 = 12288 B

    hipLaunchKernelGGL(k1_basis, dim3(4),  dim3(256), 0, stream, theta, u);
    hipLaunchKernelGGL(k2_gram,  dim3(64), dim3(256), 0, stream, u, C);
    hipLaunchKernelGGL(k3_eval,  dim3(BATCH / 256), dim3(256), 0, stream, x, C, out);
}